// Round 1
// baseline (491.700 us; speedup 1.0000x reference)
//
#include <hip/hip_runtime.h>

#define NCLS 16
#define NB 391      // ceil(100000/256) buckets of 256 node IDs
#define BSH 8       // bucket = dst >> 8, local node = dst & 255
#define TILE 4096
#define PREB 512    // blocks devoted to bhist inside pre_kernel
#define ASTR 17     // padded LDS row stride (floats) to spread banks

static __device__ __forceinline__ float bflo(unsigned u) {
  return __uint_as_float(u << 16);
}
static __device__ __forceinline__ float bfhi(unsigned u) {
  return __uint_as_float(u & 0xFFFF0000u);
}
static __device__ __forceinline__ unsigned f2bf1(float f) {
  unsigned u = __float_as_uint(f);
  return (u + 0x7FFF + ((u >> 16) & 1)) >> 16;  // RNE
}
static __device__ __forceinline__ unsigned packbf(float a, float b) {
  return f2bf1(a) | (f2bf1(b) << 16);
}

// ---- fused: bucket histogram (blocks 0..PREB-1) + f32->bf16 convert (rest) ----
__global__ void pre_kernel(const int* __restrict__ dstv, int* __restrict__ bcnt, int E,
                           const float2* __restrict__ aug, unsigned* __restrict__ augh, int n2) {
  __shared__ int lh[NB];
  if (blockIdx.x < PREB) {
    for (int t = threadIdx.x; t < NB; t += 256) lh[t] = 0;
    __syncthreads();
    int stride = PREB * 256;
    for (int i = blockIdx.x * 256 + threadIdx.x; i < E; i += stride)
      atomicAdd(&lh[dstv[i] >> BSH], 1);
    __syncthreads();
    for (int t = threadIdx.x; t < NB; t += 256) {
      int v = lh[t];
      if (v) atomicAdd(&bcnt[t], v);
    }
  } else {
    int i = (blockIdx.x - PREB) * 256 + threadIdx.x;
    if (i < n2) {
      float2 v = aug[i];
      augh[i] = packbf(v.x, v.y);
    }
  }
}

// ---- exclusive scan of 391 bucket counts (single block, 512 thr) ----
__global__ void bscan_kernel(const int* __restrict__ bcnt, int* __restrict__ bbase,
                             int* __restrict__ gcur) {
  __shared__ int tmp[512];
  int t = threadIdx.x;
  int x = (t < NB) ? bcnt[t] : 0;
  tmp[t] = x;
  __syncthreads();
  for (int o = 1; o < 512; o <<= 1) {
    int v = (t >= o) ? tmp[t - o] : 0;
    __syncthreads();
    tmp[t] += v;
    __syncthreads();
  }
  if (t < NB) { int e = tmp[t] - x; bbase[t] = e; gcur[t] = e; }
  if (t == NB - 1) bbase[NB] = tmp[t];
}

// ---- bin pass: tile-local bucket sort in LDS; stage {val, gdest}; coalesced flush ----
__global__ void __launch_bounds__(256) bin_kernel(const int* __restrict__ srcv,
                                                  const int* __restrict__ dstv,
                                                  int* __restrict__ gcur,
                                                  int* __restrict__ packed, int E) {
  __shared__ int hist[NB];
  __shared__ int off[NB];
  __shared__ int delta[NB];   // gb[b] - off[b]
  __shared__ int cur[NB];
  __shared__ int part[16];
  __shared__ int2 stag[TILE];
  int tid = threadIdx.x;
  int base = blockIdx.x * TILE;
  int cnt = min(TILE, E - base);
  for (int t = tid; t < NB; t += 256) hist[t] = 0;
  __syncthreads();
  for (int k = tid; k < cnt; k += 256)
    atomicAdd(&hist[dstv[base + k] >> BSH], 1);
  __syncthreads();
  // two-level exclusive scan of hist
  if (tid < 16) {
    int s = 0;
    int lo = tid * 25, hiX = min(NB, lo + 25);
    for (int j = lo; j < hiX; j++) { int v = hist[j]; off[j] = s; s += v; }
    part[tid] = s;
  }
  __syncthreads();
  if (tid == 0) {
    int run = 0;
    for (int j = 0; j < 16; j++) { int v = part[j]; part[j] = run; run += v; }
  }
  __syncthreads();
  for (int t = tid; t < NB; t += 256) off[t] += part[t / 25];
  __syncthreads();
  // reserve global space (one atomic per nonempty bucket) + set cur/delta
  for (int t = tid; t < NB; t += 256) {
    int c = hist[t];
    int gb = c ? atomicAdd(&gcur[t], c) : 0;
    delta[t] = gb - off[t];
    cur[t] = off[t];
  }
  __syncthreads();
  // scatter: stage value + final global destination
  for (int k = tid; k < cnt; k += 256) {
    int s = srcv[base + k], d = dstv[base + k];
    int b = d >> BSH;
    int p = atomicAdd(&cur[b], 1);
    int2 w;
    w.x = s | ((d & 255) << 17);
    w.y = p + delta[b];
    stag[p] = w;
  }
  __syncthreads();
  // flush: contiguous LDS b64 reads, segment-coalesced global stores
  for (int i = tid; i < cnt; i += 256) {
    int2 w = stag[i];
    packed[w.y] = w.x;
  }
}

// ---- agg: per-bucket scatter-mean in LDS + node math (replaces csr_sort + pull_node) ----
// one block per bucket; edges unsorted within bucket, packed word = src | local<<17.
__global__ void __launch_bounds__(1024) agg_kernel(const int* __restrict__ bbase,
                                                   const int* __restrict__ packed,
                                                   const unsigned* __restrict__ augh,
                                                   unsigned* __restrict__ logs,
                                                   float* __restrict__ dvec,
                                                   double* __restrict__ acc, int N) {
  __shared__ float sacc[256 * ASTR];  // per-node class sums, stride-17 padded
  __shared__ int cnt[256];
  __shared__ float red[16];
  int tid = threadIdx.x;
  int b = blockIdx.x;
  int rbeg = bbase[b], rend = bbase[b + 1];
  for (int i = tid; i < 256 * ASTR; i += 1024) sacc[i] = 0.f;
  if (tid < 256) cnt[tid] = 0;
  __syncthreads();
  int c0 = tid & 15;  // lane-staggered class order: spreads bank pressure
  for (int i = rbeg + tid; i < rend; i += 1024) {
    int w = packed[i];
    int src = w & 0x1FFFF;
    int local = w >> 17;
    const uint4* gp = reinterpret_cast<const uint4*>(augh + ((size_t)src << 3));
    uint4 w0 = gp[0];
    uint4 w1 = gp[1];
    atomicAdd(&cnt[local], 1);
    float v[16];
    v[0] = bflo(w0.x);  v[1] = bfhi(w0.x);  v[2] = bflo(w0.y);  v[3] = bfhi(w0.y);
    v[4] = bflo(w0.z);  v[5] = bfhi(w0.z);  v[6] = bflo(w0.w);  v[7] = bfhi(w0.w);
    v[8] = bflo(w1.x);  v[9] = bfhi(w1.x);  v[10] = bflo(w1.y); v[11] = bfhi(w1.y);
    v[12] = bflo(w1.z); v[13] = bfhi(w1.z); v[14] = bflo(w1.w); v[15] = bfhi(w1.w);
    float* row = sacc + local * ASTR;
#pragma unroll
    for (int k = 0; k < 16; k++) {
      int c = (c0 + k) & 15;
      atomicAdd(&row[c], v[c]);
    }
  }
  __syncthreads();
  float contrib = 0.f;
  if (tid < 256) {
    int g = (b << BSH) + tid;
    if (g < N) {
      int deg = cnt[tid];
      float inv = 1.0f / fmaxf((float)deg, 1.0f);
      const float* row = sacc + tid * ASTR;
      float a[16];
      float p2 = 0.f;
#pragma unroll
      for (int c = 0; c < 16; c++) {
        a[c] = row[c] * inv;
        p2 += a[c] * a[c];
      }
      float ip = 1.0f / p2;
      float d[16];
      float h = 0.f;
#pragma unroll
      for (int c = 0; c < 16; c++) {
        d[c] = a[c] * a[c] * ip + 1e-10f;
        h += d[c] * __logf(d[c]);
      }
      uint4 lw0, lw1;
      lw0.x = packbf(__logf(a[0] + 1e-10f), __logf(a[1] + 1e-10f));
      lw0.y = packbf(__logf(a[2] + 1e-10f), __logf(a[3] + 1e-10f));
      lw0.z = packbf(__logf(a[4] + 1e-10f), __logf(a[5] + 1e-10f));
      lw0.w = packbf(__logf(a[6] + 1e-10f), __logf(a[7] + 1e-10f));
      lw1.x = packbf(__logf(a[8] + 1e-10f), __logf(a[9] + 1e-10f));
      lw1.y = packbf(__logf(a[10] + 1e-10f), __logf(a[11] + 1e-10f));
      lw1.z = packbf(__logf(a[12] + 1e-10f), __logf(a[13] + 1e-10f));
      lw1.w = packbf(__logf(a[14] + 1e-10f), __logf(a[15] + 1e-10f));
      uint4* lp = reinterpret_cast<uint4*>(logs + ((size_t)g << 3));
      lp[0] = lw0;
      lp[1] = lw1;
      float4* dp = reinterpret_cast<float4*>(dvec + ((size_t)g << 4));
      float4 dd;
      dd.x = d[0];  dd.y = d[1];  dd.z = d[2];  dd.w = d[3];  dp[0] = dd;
      dd.x = d[4];  dd.y = d[5];  dd.z = d[6];  dd.w = d[7];  dp[1] = dd;
      dd.x = d[8];  dd.y = d[9];  dd.z = d[10]; dd.w = d[11]; dp[2] = dd;
      dd.x = d[12]; dd.y = d[13]; dd.z = d[14]; dd.w = d[15]; dp[3] = dd;
      contrib = (float)deg * h;
    }
  }
#pragma unroll
  for (int o = 32; o >= 1; o >>= 1) contrib += __shfl_xor(contrib, o, 64);
  if ((tid & 63) == 0) red[tid >> 6] = contrib;
  __syncthreads();
  if (tid == 0) {
    float s = 0.f;
#pragma unroll
    for (int wv = 0; wv < 16; wv++) s += red[wv];
    atomicAdd(acc, (double)s);
  }
}

// ---- loss: per-bucket dvec in LDS; stream edges; gather logs[src]; dot ----
__global__ void __launch_bounds__(1024) loss_kernel(const int* __restrict__ bbase,
                                                    const int* __restrict__ packed,
                                                    const unsigned* __restrict__ logs,
                                                    const float* __restrict__ dvec,
                                                    double* __restrict__ acc, int N) {
  __shared__ float sdv[256 * ASTR];
  __shared__ float red[16];
  int tid = threadIdx.x;
  int b = blockIdx.x;
  int rbeg = bbase[b], rend = bbase[b + 1];
  int nb0 = b << BSH;
  {
    const float4* gsrc = reinterpret_cast<const float4*>(dvec + ((size_t)nb0 << 4));
    int nvalid = min(256, N - nb0);
    int nf4 = nvalid * 4;
    for (int i = tid; i < nf4; i += 1024) {
      float4 v = gsrc[i];
      float* r = sdv + (i >> 2) * ASTR + ((i & 3) << 2);
      r[0] = v.x; r[1] = v.y; r[2] = v.z; r[3] = v.w;
    }
  }
  __syncthreads();
  float dot = 0.f;
  for (int i = rbeg + tid; i < rend; i += 1024) {
    int w = packed[i];
    int src = w & 0x1FFFF;
    int local = w >> 17;
    const uint4* gp = reinterpret_cast<const uint4*>(logs + ((size_t)src << 3));
    uint4 w0 = gp[0];
    uint4 w1 = gp[1];
    const float* row = sdv + local * ASTR;
    dot += row[0] * bflo(w0.x) + row[1] * bfhi(w0.x) +
           row[2] * bflo(w0.y) + row[3] * bfhi(w0.y) +
           row[4] * bflo(w0.z) + row[5] * bfhi(w0.z) +
           row[6] * bflo(w0.w) + row[7] * bfhi(w0.w) +
           row[8] * bflo(w1.x) + row[9] * bfhi(w1.x) +
           row[10] * bflo(w1.y) + row[11] * bfhi(w1.y) +
           row[12] * bflo(w1.z) + row[13] * bfhi(w1.z) +
           row[14] * bflo(w1.w) + row[15] * bfhi(w1.w);
  }
#pragma unroll
  for (int o = 32; o >= 1; o >>= 1) dot += __shfl_xor(dot, o, 64);
  if ((tid & 63) == 0) red[tid >> 6] = dot;
  __syncthreads();
  if (tid == 0) {
    float s = 0.f;
#pragma unroll
    for (int wv = 0; wv < 16; wv++) s += red[wv];
    atomicAdd(acc, -(double)s);
  }
}

__global__ void finalize_kernel(const double* __restrict__ acc,
                                float* __restrict__ out, int E) {
  if (threadIdx.x == 0 && blockIdx.x == 0)
    out[0] = (float)(acc[0] / (double)E);
}

extern "C" void kernel_launch(void* const* d_in, const int* in_sizes, int n_in,
                              void* d_out, int out_size, void* d_ws, size_t ws_size,
                              hipStream_t stream) {
  const int* edge_index = (const int*)d_in[0];
  const float* aug_pred = (const float*)d_in[1];
  const int E = in_sizes[0] / 2;
  const int N = in_sizes[1] / NCLS;

  const int* srcv = edge_index;
  const int* dstv = edge_index + E;

  // 256B-aligned bump allocator over d_ws
  char* p = (char*)d_ws;
  auto alloc = [&](size_t bytes) {
    char* r = p;
    p += (bytes + 255) & ~(size_t)255;
    return r;
  };
  double* acc = (double*)alloc(8);
  int* bcnt = (int*)alloc(NB * 4);
  int* bbase = (int*)alloc((NB + 1) * 4);
  int* gcur = (int*)alloc(NB * 4);
  int* packed = (int*)alloc((size_t)E * 4);
  unsigned* augh = (unsigned*)alloc((size_t)N * NCLS * 2);
  unsigned* logs = (unsigned*)alloc((size_t)N * NCLS * 2);
  float* dvec = (float*)alloc((size_t)N * NCLS * 4);

  // zero acc + bcnt (contiguous prefix of the arena)
  size_t zero_bytes = (size_t)((char*)bbase - (char*)d_ws);
  hipMemsetAsync(d_ws, 0, zero_bytes, stream);

  int n2 = N * NCLS / 2;
  int cvtb = (n2 + 255) / 256;
  pre_kernel<<<PREB + cvtb, 256, 0, stream>>>(dstv, bcnt, E, (const float2*)aug_pred, augh, n2);
  bscan_kernel<<<1, 512, 0, stream>>>(bcnt, bbase, gcur);
  int tiles = (E + TILE - 1) / TILE;
  bin_kernel<<<tiles, 256, 0, stream>>>(srcv, dstv, gcur, packed, E);
  agg_kernel<<<NB, 1024, 0, stream>>>(bbase, packed, augh, logs, dvec, acc, N);
  loss_kernel<<<NB, 1024, 0, stream>>>(bbase, packed, logs, dvec, acc, N);
  finalize_kernel<<<1, 64, 0, stream>>>(acc, (float*)d_out, E);
}